// Round 10
// baseline (235.911 us; speedup 1.0000x reference)
//
#include <hip/hip_runtime.h>
#include <math.h>

// Problem constants
#define NB 128     // batch
#define NC 128     // channels
#define NN 170     // nodes
#define NT 12      // length
#define NP 192     // padded node count (12 tiles of 16)
#define MP 176     // P row stride (halfs)
#define XSTR 192   // xs row stride (halfs), pads [170,192) zeroed by k1

// Workspace regions (halfs)
#define EST_SZ ((size_t)NP * NC)            //    24,576 halfs (48 KB)
#define XS_SZ  ((size_t)NB * NC * XSTR)     // 3,145,728 halfs (6.3 MB)
#define P_SZ   ((size_t)NB * NN * MP)       // 3,829,760 halfs (7.3 MB)

typedef _Float16 h8 __attribute__((ext_vector_type(8)));
typedef float    f4 __attribute__((ext_vector_type(4)));

// tanh via hw exp+rcp: ~6 VALU ops. rel err ~1e-6. Clamp sanitizes inf.
__device__ __forceinline__ float fast_tanh(float x) {
    float cx = fminf(fmaxf(x, -15.f), 15.f);
    float e  = __expf(2.f * cx);
    return (e - 1.f) * __builtin_amdgcn_rcpf(e + 1.f);
}

// ---------------------------------------------------------------------------
// K1 (TA-minimal t-sum + Est transpose tail).
// R5-R9 evidence: every phase-1 variant gave each lane a >=48B private span,
// so each 64-lane load instruction spanned 48-96 cache lines (3-6x the
// coalesced minimum of 16) and all variants pinned at the same ~2-3.5 TB/s
// regardless of barriers/pipelining. The 6.9 TB/s fill is lane-contiguous.
// THIS KERNEL makes the x read lane-contiguous: one WAVE owns one (b,c) row
// (2040 floats). Per 64-node group: 3 contiguous wave-wide float4 loads
// (1KB payload = 16 lines each), bounce through wave-private LDS (padded
// slot' = s + (s>>2): write/read conflicts <=2-way = free), 12-float reg
// sum, one 128B-contiguous f16 store. ZERO barriers (DS ops are per-wave
// in-order; explicit lgkmcnt(0) between write and read). LDS 15.4 KB/block,
// tiny VGPR -> 8 blocks/CU = full 32-wave occupancy.
// Blocks [4096,4192): Est[m][c] = f16(Es[c][m]), rows m in [170,192) zero.
// xs pad cols [170,192) are stored as exact 0 (masked loads sum to 0).
// ---------------------------------------------------------------------------
__global__ __launch_bounds__(256) void k1_tsum_est(const float* __restrict__ x,
                                                   const float* __restrict__ Es,
                                                   _Float16* __restrict__ xs,
                                                   _Float16* __restrict__ Est) {
    const int bid = blockIdx.x;
    const int t = threadIdx.x;
    if (bid < 4096) {
        const int wave = t >> 6, lane = t & 63;
        const int bc = bid * 4 + wave;              // [0, 16384) = b*128 + c
        __shared__ __align__(16) float4 S4[4][240]; // 15,360 B wave-private
        float4* S = S4[wave];
        const float4* xr = reinterpret_cast<const float4*>(x + (size_t)bc * (NN * NT));
        _Float16* xsr = xs + (size_t)bc * XSTR;
        #pragma unroll
        for (int g = 0; g < 3; ++g) {               // 64 nodes per group
            float4 v[3];
            #pragma unroll
            for (int j = 0; j < 3; ++j) {           // 3x wave-contiguous 1KB
                int s = g * 192 + j * 64 + lane;    // row has 510 float4
                v[j] = (s < 510) ? xr[s] : make_float4(0.f, 0.f, 0.f, 0.f);
            }
            #pragma unroll
            for (int j = 0; j < 3; ++j) {           // padded slot': s + (s>>2)
                int s = j * 64 + lane;
                S[s + (s >> 2)] = v[j];
            }
            asm volatile("s_waitcnt lgkmcnt(0)" ::: "memory");
            int s0 = 3 * lane, s1 = s0 + 1, s2 = s0 + 2;  // node = 12 floats
            float4 a0 = S[s0 + (s0 >> 2)];
            float4 a1 = S[s1 + (s1 >> 2)];
            float4 a2 = S[s2 + (s2 >> 2)];
            float sv = ((a0.x + a0.y) + (a0.z + a0.w))
                     + ((a1.x + a1.y) + (a1.z + a1.w))
                     + ((a2.x + a2.y) + (a2.z + a2.w));
            // n in [170,192): masked loads => sv == 0 exactly (zeroes the pad)
            xsr[g * 64 + lane] = (_Float16)sv;      // 128B contiguous per wave
            asm volatile("s_waitcnt lgkmcnt(0)" ::: "memory");  // reads done before next g's writes (WAR; DS in-order anyway)
        }
    } else {
        int idx = (bid - 4096) * 256 + t;           // [0, 192*128)
        int m = idx >> 7, c = idx & 127;
        Est[idx] = (m < NN) ? (_Float16)Es[c * NN + m] : (_Float16)0.f;
    }
}

// ---------------------------------------------------------------------------
// KB — grid (2,128): block (h,b) = output-row half h of batch b. 512 threads
// = 8 waves = 2/SIMD (VGPR cap 256, unlike the 1024-thread kA's 64-cap that
// strangled load ILP). Stages At = xs[b]^T (48 KB, L3-hot) into swizzled
// LDS, then the R7/R9-proven GEMM1 -> EdL(LDS) -> GEMM2 -> softmax -> P.
// All MFMA/swizzle patterns are the HW-verified family: A*B^T, operands
// k-contiguous h8 at quad*8; D: col=lane&15, row=quad*4+reg; XOR swizzle
// group' = group ^ (row&7) on 16B groups.
// LDS: 49,152 (At/Sc) + 73,728 (EdL) = 122,880 B -> 1 block/CU.
// ---------------------------------------------------------------------------
#define ATSW(row, c)  ((row) * 128 + (((((c) >> 3) ^ ((row) & 7)) << 3) | ((c) & 7)))
#define EDSW(row, m)  ((row) * 192 + (((((m) >> 3) ^ ((row) & 7)) << 3) | ((m) & 7)))
#define SCSTR 204

__global__ __launch_bounds__(512) void kB_fused(const _Float16* __restrict__ xs,
                                                const _Float16* __restrict__ Est,
                                                _Float16* __restrict__ P) {
    const int h = blockIdx.x, b = blockIdx.y;
    const int r0 = h * 96;                          // this block's output rows
    const int t = threadIdx.x;                      // [0,512)
    const int lane = t & 63, wave = t >> 6;         // wave [0,8)
    const int l15 = lane & 15, quad = lane >> 4;

    __shared__ __align__(16) char     UN[192 * 128 * 2]; // 49,152 B At, later Sc
    __shared__ __align__(16) _Float16 EdL[192 * 192];    // 73,728 B
    _Float16* At = (_Float16*)UN;                   // [192 n][128 c] swizzled
    float*    Sc = (float*)UN;                      // [48][SCSTR] f32 (39,168 B)

    // ---- stage At = xs[b]^T: 3072 h8 loads, 8 b16 scatter each ----
    // ds_write pattern: lanes cover 64 consecutive c = 8 XOR'd 16B segments
    // = all 32 banks exactly once (bijective XOR) -> conflict-free.
    const _Float16* __restrict__ xsb = xs + (size_t)b * NC * XSTR;
    #pragma unroll
    for (int i = 0; i < 6; ++i) {
        int idx = t + i * 512;                      // [0,3072) = 24 ng x 128 c
        int ng = idx >> 7, c = idx & 127;
        h8 v = *reinterpret_cast<const h8*>(xsb + (size_t)c * XSTR + ng * 8);
        #pragma unroll
        for (int j = 0; j < 8; ++j)
            At[ATSW(ng * 8 + j, c)] = v[j];         // pad rows arrive as 0
    }
    __syncthreads();

    // ---- GEMM1: EdL = tanh(At · Est^T); wave: 48 rows x 96 cols ----
    {
        const int wr = wave >> 1, wh = wave & 1;
        f4 acc1[3][6] = {};
        #pragma unroll
        for (int kk = 0; kk < 4; ++kk) {            // K = 128
            int ks = kk * 32 + quad * 8;
            h8 a[3], bf[6];
            #pragma unroll
            for (int rt = 0; rt < 3; ++rt) {
                int row = wr * 48 + rt * 16 + l15;
                a[rt] = *reinterpret_cast<const h8*>(
                    &At[row * 128 + (((ks >> 3) ^ (row & 7)) << 3)]);
            }
            #pragma unroll
            for (int ci = 0; ci < 6; ++ci) {
                int m = wh * 96 + ci * 16 + l15;
                bf[ci] = *reinterpret_cast<const h8*>(Est + (size_t)m * NC + ks);
            }
            #pragma unroll
            for (int rt = 0; rt < 3; ++rt)
                #pragma unroll
                for (int ci = 0; ci < 6; ++ci)
                    acc1[rt][ci] = __builtin_amdgcn_mfma_f32_16x16x32_f16(
                        a[rt], bf[ci], acc1[rt][ci], 0, 0, 0);
        }
        // epilogue: tanh -> EdL (swizzled b16 writes; pad rows/cols exact 0)
        #pragma unroll
        for (int rt = 0; rt < 3; ++rt)
            #pragma unroll
            for (int ci = 0; ci < 6; ++ci) {
                int m = (wave & 1) * 96 + ci * 16 + l15;
                #pragma unroll
                for (int reg = 0; reg < 4; ++reg) {
                    int n = (wave >> 1) * 48 + rt * 16 + quad * 4 + reg;
                    EdL[EDSW(n, m)] = (_Float16)fast_tanh(acc1[rt][ci][reg]);
                }
            }
    }
    __syncthreads();                                // EdL complete; At dead

    // ---- GEMM2: rows [r0,r0+96) x cols [0,192); wave (gr,gc): 48x48 ----
    f4 acc2[3][3] = {};
    {
        const int gr = wave >> 2, gc = wave & 3;    // all 8 waves active
        #pragma unroll 2
        for (int mc = 0; mc < 192; mc += 32) {      // K = 192 (pad cols are 0)
            int mg = (mc >> 3) + quad;
            h8 a2[3], b2[3];
            #pragma unroll
            for (int rt = 0; rt < 3; ++rt) {
                int row = r0 + gr * 48 + rt * 16 + l15;
                a2[rt] = *reinterpret_cast<const h8*>(
                    &EdL[row * 192 + ((mg ^ (row & 7)) << 3)]);
            }
            #pragma unroll
            for (int ci = 0; ci < 3; ++ci) {
                int row = gc * 48 + ci * 16 + l15;  // score col base
                b2[ci] = *reinterpret_cast<const h8*>(
                    &EdL[row * 192 + ((mg ^ (row & 7)) << 3)]);
            }
            #pragma unroll
            for (int rt = 0; rt < 3; ++rt)
                #pragma unroll
                for (int ci = 0; ci < 3; ++ci)
                    acc2[rt][ci] = __builtin_amdgcn_mfma_f32_16x16x32_f16(
                        a2[rt], b2[ci], acc2[rt][ci], 0, 0, 0);
        }
    }

    // ---- 2 rounds of 48 rows: scatter (waves gr==p) -> softmax (all) ----
    const float scale = 0.08838834764831845f;       // 1/sqrt(128)
    for (int p = 0; p < 2; ++p) {
        __syncthreads();                            // prev round's Sc reads done
        if ((wave >> 2) == p) {                     // 4 waves cover 4 col-groups
            const int gc = wave & 3;
            #pragma unroll
            for (int rt = 0; rt < 3; ++rt)
                #pragma unroll
                for (int ci = 0; ci < 3; ++ci) {
                    int col = gc * 48 + ci * 16 + l15;
                    #pragma unroll
                    for (int reg = 0; reg < 4; ++reg) {
                        int rloc = rt * 16 + quad * 4 + reg;
                        Sc[rloc * SCSTR + col] = fmaxf(acc2[rt][ci][reg] * scale, 0.f);
                    }
                }
        }
        __syncthreads();
        // proven wave-parallel softmax; wave owns 6 rows of this 48-row round
        #pragma unroll
        for (int rr = 0; rr < 6; ++rr) {
            int r = wave * 6 + rr;
            int n = r0 + p * 48 + r;
            if (n >= NN) continue;
            float v0 = Sc[r * SCSTR + lane];
            float v1 = Sc[r * SCSTR + lane + 64];
            int  k2i = lane + 128;
            bool has2 = (k2i < NN);
            float v2 = has2 ? Sc[r * SCSTR + k2i] : -1.f;
            float m = fmaxf(fmaxf(v0, v1), v2);
            #pragma unroll
            for (int off = 32; off; off >>= 1) m = fmaxf(m, __shfl_xor(m, off, 64));
            float e0 = __expf(v0 - m);
            float e1 = __expf(v1 - m);
            float e2 = has2 ? __expf(v2 - m) : 0.f;
            float s = e0 + e1 + e2;
            #pragma unroll
            for (int off = 32; off; off >>= 1) s += __shfl_xor(s, off, 64);
            float inv = 1.f / s;
            _Float16* Pr = P + ((size_t)(b * NN + n)) * MP;
            Pr[lane]      = (_Float16)(e0 * inv);
            Pr[lane + 64] = (_Float16)(e1 * inv);
            if (has2) Pr[k2i] = (_Float16)(e2 * inv);
        }
    }
}

// ---------------------------------------------------------------------------
// K4: mean over batch + threshold in one pass, 8-way accumulator ILP. Proven.
// ---------------------------------------------------------------------------
__global__ __launch_bounds__(256) void k4_mean_thresh(const _Float16* __restrict__ P,
                                                      float* __restrict__ out) {
    int p = blockIdx.x * 256 + threadIdx.x;
    if (p >= NN * NN) return;
    int n = p / NN, k = p - n * NN;
    const _Float16* base = P + (size_t)n * MP + k;
    float s0 = 0.f, s1 = 0.f, s2 = 0.f, s3 = 0.f;
    float s4 = 0.f, s5 = 0.f, s6 = 0.f, s7 = 0.f;
    #pragma unroll
    for (int b = 0; b < NB; b += 8) {
        s0 += (float)base[(size_t)(b + 0) * NN * MP];
        s1 += (float)base[(size_t)(b + 1) * NN * MP];
        s2 += (float)base[(size_t)(b + 2) * NN * MP];
        s3 += (float)base[(size_t)(b + 3) * NN * MP];
        s4 += (float)base[(size_t)(b + 4) * NN * MP];
        s5 += (float)base[(size_t)(b + 5) * NN * MP];
        s6 += (float)base[(size_t)(b + 6) * NN * MP];
        s7 += (float)base[(size_t)(b + 7) * NN * MP];
    }
    float s = ((s0 + s1) + (s2 + s3)) + ((s4 + s5) + (s6 + s7));
    out[p] = (s * (1.f / 128.f) > 0.5f) ? 1.f : 0.f;
}

// ---------------------------------------------------------------------------
// Workspace layout (halfs):
//   [0, EST_SZ)   : Est (f16, [192][128])      live through KB
//   [+, +XS_SZ)   : xs  (f16, [b*128+c][192])  dead after KB
//   [+, +P_SZ)    : P   (f16, [b][n][176])     dead after K4
// Total = 14.0 MB.
// ---------------------------------------------------------------------------
extern "C" void kernel_launch(void* const* d_in, const int* in_sizes, int n_in,
                              void* d_out, int out_size, void* d_ws, size_t ws_size,
                              hipStream_t stream) {
    const float* x  = (const float*)d_in[0];   // [128,128,170,12] f32
    const float* Es = (const float*)d_in[1];   // [128,170] f32
    float* out = (float*)d_out;                // [170,170] f32

    _Float16* Est = (_Float16*)d_ws;
    _Float16* xs  = Est + EST_SZ;
    _Float16* P   = xs + XS_SZ;

    k1_tsum_est<<<4192, 256, 0, stream>>>(x, Es, xs, Est);
    kB_fused<<<dim3(2, 128), 512, 0, stream>>>(xs, Est, P);
    k4_mean_thresh<<<113, 256, 0, stream>>>(P, out);
}